// Round 2
// baseline (978.243 us; speedup 1.0000x reference)
//
#include <hip/hip_runtime.h>
#include <hip/hip_bf16.h>
#include <cstdint>
#include <cstddef>

// ---------------------------------------------------------------------------
// LocalAttentionModel (MI355X / gfx950)
// x:(8,128,128,320) fp32 -> row-mask -> qkv = xs@w_in^T+b -> banded attn
// (|i-j|<=3) -> o@w_out^T+b -> LayerNorm(320).
//
// Design (round 1): minimize workspace + fuse.
//   K0 detect_mask : resolves pad_mask storage (bool-1B vs int32) at runtime.
//   K1 qkv_attn    : per block = one sequence (128 rows). For each of 5
//                    head-pairs: 3-term-split bf16 MFMA GEMM (128x192, K=320)
//                    -> QKV in LDS -> banded softmax -> O written hi/lo bf16.
//                    qkv NEVER touches global memory.
//   K2 proj_ln     : 128x320 tile (full row) 3-term GEMM + fused LayerNorm
//                    epilogue -> writes final output directly.
// Workspace use: 256 B flag + 2 x 80 MB (O hi/lo) = 160 MB.
// Numerics: A=Ah+Al, B=Bh+Bl (bf16); C ~= AhBh+AhBl+AlBh, rel err ~2^-17.
// ---------------------------------------------------------------------------

#define DIM   320
#define HEADS 10
#define LSEQ  128
#define NSEQ  1024
#define MROWS (NSEQ * LSEQ)

typedef __attribute__((ext_vector_type(8))) __bf16 bf16x8;
typedef __attribute__((ext_vector_type(4))) float  f32x4;

#define PADK 40        // LDS row stride (elems) for 32-wide K tiles: 80B, 16B-aligned, ~2-way banks
#define QVP  4616      // per-head fp32 stride: 128*36 + 8 (row pad 36, +8 head skew)

// split 8 contiguous fp32 into hi/lo bf16 (with optional row multiplier)
__device__ __forceinline__ void split8(const float* __restrict__ src, float mult,
                                       bf16x8& h, bf16x8& l) {
  float4 v0 = *(const float4*)src;
  float4 v1 = *(const float4*)(src + 4);
  float f[8] = {v0.x, v0.y, v0.z, v0.w, v1.x, v1.y, v1.z, v1.w};
#pragma unroll
  for (int j = 0; j < 8; ++j) {
    float t = f[j] * mult;
    __bf16 hb = (__bf16)t;
    h[j] = hb;
    l[j] = (__bf16)(t - (float)hb);
  }
}

// ---------------------------------------------------------------------------
// K0: detect pad_mask storage. Scans only the first n BYTES (in-bounds for
// both bool[n] and int32[n]). int32 0/1 values have zero bytes at i%4!=0;
// bool random 0/1 data has ~50% nonzero there. flag=1 -> bool layout.
// ---------------------------------------------------------------------------
__global__ __launch_bounds__(1024) void detect_mask_kernel(
    const unsigned char* __restrict__ pm, int n, int* __restrict__ flag) {
  __shared__ int s;
  if (threadIdx.x == 0) s = 0;
  __syncthreads();
  int nz = 0;
  for (int i = threadIdx.x; i < n; i += 1024)
    if ((i & 3) && pm[i]) nz = 1;
  if (nz) atomicOr(&s, 1);
  __syncthreads();
  if (threadIdx.x == 0) *flag = s;
}

// ---------------------------------------------------------------------------
// K1: fused QKV GEMM + banded attention. One block (512 thr, 8 waves) per
// sequence. Wave grid 2x4 over a 128x192 tile (2 heads' q,k,v columns).
// ---------------------------------------------------------------------------
__global__ __launch_bounds__(512, 2) void qkv_attn_kernel(
    const float* __restrict__ x, const float* __restrict__ w_in,
    const float* __restrict__ b_in, const void* __restrict__ pm,
    const int* __restrict__ flag, __bf16* __restrict__ oh,
    __bf16* __restrict__ ol) {
  __shared__ __align__(16) __bf16 sAh[128 * PADK];
  __shared__ __align__(16) __bf16 sAl[128 * PADK];
  __shared__ __align__(16) __bf16 sBh[192 * PADK];
  __shared__ __align__(16) __bf16 sBl[192 * PADK];
  __shared__ __align__(16) float  sQKV[3][2 * QVP];   // [q|k|v][head*QVP + row*36 + dim]
  // total LDS = 20480 + 30720 + 110784 = 161,984 B  (<= 160 KiB)

  const int tid  = threadIdx.x;
  const int seq  = blockIdx.x;
  const int lane = tid & 63;
  const int wid  = tid >> 6;
  const int wm = wid >> 2, wn = wid & 3;        // 2 x 4 wave grid
  const int lr = lane & 15, kc = (lane >> 4) * 8;

  // A staging: each thread owns (row = tid>>2, 8-elem chunk = tid&3), fixed all kernel
  const int arow = tid >> 2, ach = tid & 3;
  const int grow = seq * LSEQ + arow;
  const float* aptr = x + (size_t)grow * DIM + ach * 8;
  const int mv = (*flag) ? (int)((const unsigned char*)pm)[grow]
                         : ((const int*)pm)[grow];
  const float mult = mv ? 0.f : 1.f;            // mask==true -> zero the row

  // attention thread mapping: (q row, head-of-pair, 16-dim half)
  const int q = tid >> 2, hh = (tid >> 1) & 1, hf = tid & 1;

  for (int hp = 0; hp < 5; ++hp) {              // head pairs
    f32x4 acc[4][3];
#pragma unroll
    for (int mt = 0; mt < 4; ++mt)
#pragma unroll
      for (int nt = 0; nt < 3; ++nt)
#pragma unroll
        for (int r = 0; r < 4; ++r) acc[mt][nt][r] = 0.f;

    for (int kt = 0; kt < 10; ++kt) {           // K = 320, BK = 32
      __syncthreads();                          // LDS safe to overwrite
      {                                         // stage A (fp32 -> hi/lo, masked)
        bf16x8 h, l;
        split8(aptr + kt * 32, mult, h, l);
        *(bf16x8*)&sAh[arow * PADK + ach * 8] = h;
        *(bf16x8*)&sAl[arow * PADK + ach * 8] = l;
      }
#pragma unroll
      for (int it = 0; it < 2; ++it) {          // stage B: 192 rows x 32 (fp32 -> hi/lo)
        int c = tid + it * 512;
        if (c < 768) {
          int row = c >> 2, ch = c & 3;
          int g = row >> 5, type = g % 3, hl = g / 3;   // [q0,k0,v0,q1,k1,v1]
          int wrow = type * DIM + (hp * 2 + hl) * 32 + (row & 31);
          bf16x8 h, l;
          split8(w_in + (size_t)wrow * DIM + kt * 32 + ch * 8, 1.f, h, l);
          *(bf16x8*)&sBh[row * PADK + ch * 8] = h;
          *(bf16x8*)&sBl[row * PADK + ch * 8] = l;
        }
      }
      __syncthreads();                          // staging visible
      bf16x8 ah[4], al[4], bh[3], bl[3];
#pragma unroll
      for (int mt = 0; mt < 4; ++mt) {
        int o = (wm * 64 + mt * 16 + lr) * PADK + kc;
        ah[mt] = *(const bf16x8*)&sAh[o];
        al[mt] = *(const bf16x8*)&sAl[o];
      }
#pragma unroll
      for (int nt = 0; nt < 3; ++nt) {
        int o = (wn * 48 + nt * 16 + lr) * PADK + kc;
        bh[nt] = *(const bf16x8*)&sBh[o];
        bl[nt] = *(const bf16x8*)&sBl[o];
      }
#pragma unroll
      for (int mt = 0; mt < 4; ++mt)
#pragma unroll
        for (int nt = 0; nt < 3; ++nt) {
          acc[mt][nt] = __builtin_amdgcn_mfma_f32_16x16x32_bf16(ah[mt], bh[nt], acc[mt][nt], 0, 0, 0);
          acc[mt][nt] = __builtin_amdgcn_mfma_f32_16x16x32_bf16(ah[mt], bl[nt], acc[mt][nt], 0, 0, 0);
          acc[mt][nt] = __builtin_amdgcn_mfma_f32_16x16x32_bf16(al[mt], bh[nt], acc[mt][nt], 0, 0, 0);
        }
    }

    // scatter QKV (+bias) to LDS. C/D layout: col=lane&15, row=(lane>>4)*4+reg.
    const int g4 = lane >> 4;
#pragma unroll
    for (int nt = 0; nt < 3; ++nt) {
      const int cb = wn * 48 + nt * 16;          // 16-col block never straddles a 32-group
      const int g = cb >> 5, type = g % 3, hl = g / 3;
      const int dim = (cb & 31) + lr;
      const float bv = b_in[type * DIM + (hp * 2 + hl) * 32 + dim];
      float* dst = &sQKV[type][hl * QVP + dim];
#pragma unroll
      for (int mt = 0; mt < 4; ++mt)
#pragma unroll
        for (int r = 0; r < 4; ++r) {
          int row = wm * 64 + mt * 16 + g4 * 4 + r;
          dst[row * 36] = acc[mt][nt][r] + bv;
        }
    }
    __syncthreads();                             // QKV complete

    // banded attention: thread = (q, hh, 16-dim half). 7-key band.
    {
      const float* Qp = &sQKV[0][hh * QVP + q * 36 + hf * 16];
      float qv[16];
#pragma unroll
      for (int j4 = 0; j4 < 4; ++j4) {
        float4 t = *(const float4*)(Qp + j4 * 4);
        qv[j4 * 4 + 0] = t.x; qv[j4 * 4 + 1] = t.y;
        qv[j4 * 4 + 2] = t.z; qv[j4 * 4 + 3] = t.w;
      }
      float sc[7];
#pragma unroll
      for (int dj = 0; dj < 7; ++dj) {
        const int j = q - 3 + dj;
        const bool valid = (j >= 0) && (j < LSEQ);
        float s = 0.f;
        if (valid) {
          const float* Kp = &sQKV[1][hh * QVP + j * 36 + hf * 16];
#pragma unroll
          for (int i = 0; i < 16; ++i) s = fmaf(qv[i], Kp[i], s);
        }
        s += __shfl_xor(s, 1);                   // combine the two halves
        sc[dj] = valid ? s * 0.17677669529663687f : -1e30f;   // 1/sqrt(32)
      }
      float mx = sc[0];
#pragma unroll
      for (int dj = 1; dj < 7; ++dj) mx = fmaxf(mx, sc[dj]);
      float w[7], wsum = 0.f;
#pragma unroll
      for (int dj = 0; dj < 7; ++dj) { w[dj] = __expf(sc[dj] - mx); wsum += w[dj]; }
      const float inv = 1.f / wsum;

      float o[16];
#pragma unroll
      for (int i = 0; i < 16; ++i) o[i] = 0.f;
#pragma unroll
      for (int dj = 0; dj < 7; ++dj) {
        const int j = q - 3 + dj;
        if (j >= 0 && j < LSEQ) {
          const float ww = w[dj] * inv;
          const float* Vp = &sQKV[2][hh * QVP + j * 36 + hf * 16];
#pragma unroll
          for (int i = 0; i < 16; ++i) o[i] = fmaf(ww, Vp[i], o[i]);
        }
      }
      bf16x8 h0, h1, l0, l1;
#pragma unroll
      for (int i = 0; i < 8; ++i) {
        __bf16 a = (__bf16)o[i];
        h0[i] = a; l0[i] = (__bf16)(o[i] - (float)a);
        __bf16 b = (__bf16)o[i + 8];
        h1[i] = b; l1[i] = (__bf16)(o[i + 8] - (float)b);
      }
      const size_t ob = (size_t)(seq * LSEQ + q) * DIM + (hp * 2 + hh) * 32 + hf * 16;
      *(bf16x8*)(oh + ob)     = h0;
      *(bf16x8*)(oh + ob + 8) = h1;
      *(bf16x8*)(ol + ob)     = l0;
      *(bf16x8*)(ol + ob + 8) = l1;
    }
    // next hp: first barrier of the kt-loop orders attention-reads vs restaging
  }
}

// ---------------------------------------------------------------------------
// K2: projection GEMM (128 x 320 full-width tile) + fused LayerNorm epilogue.
// 512 threads, wave grid 2x4, MT=4, NT=5.
// ---------------------------------------------------------------------------
__global__ __launch_bounds__(512, 2) void proj_ln_kernel(
    const __bf16* __restrict__ oh, const __bf16* __restrict__ ol,
    const float* __restrict__ w_out, const float* __restrict__ b_out,
    const float* __restrict__ ln_g, const float* __restrict__ ln_b,
    float* __restrict__ out) {
  __shared__ __align__(16) __bf16 sAh[128 * PADK];
  __shared__ __align__(16) __bf16 sAl[128 * PADK];
  __shared__ __align__(16) __bf16 sBh[320 * PADK];
  __shared__ __align__(16) __bf16 sBl[320 * PADK];
  __shared__ float sSum[128 * 4], sSq[128 * 4], sMean[128], sRstd[128];

  const int tid  = threadIdx.x;
  const int bm   = blockIdx.x;
  const int lane = tid & 63, wid = tid >> 6;
  const int wm = wid >> 2, wn = wid & 3;
  const int lr = lane & 15, kc = (lane >> 4) * 8;
  const int arow = tid >> 2, ach = tid & 3;
  const __bf16* ahp = oh + (size_t)(bm * 128 + arow) * DIM + ach * 8;
  const __bf16* alp = ol + (size_t)(bm * 128 + arow) * DIM + ach * 8;

  f32x4 acc[4][5];
#pragma unroll
  for (int mt = 0; mt < 4; ++mt)
#pragma unroll
    for (int nt = 0; nt < 5; ++nt)
#pragma unroll
      for (int r = 0; r < 4; ++r) acc[mt][nt][r] = 0.f;

  for (int kt = 0; kt < 10; ++kt) {
    __syncthreads();
    *(bf16x8*)&sAh[arow * PADK + ach * 8] = *(const bf16x8*)(ahp + kt * 32);
    *(bf16x8*)&sAl[arow * PADK + ach * 8] = *(const bf16x8*)(alp + kt * 32);
#pragma unroll
    for (int it = 0; it < 3; ++it) {             // w_out: 320 rows x 32, fp32 -> hi/lo
      int c = tid + it * 512;
      if (c < 1280) {
        int row = c >> 2, ch = c & 3;
        bf16x8 h, l;
        split8(w_out + (size_t)row * DIM + kt * 32 + ch * 8, 1.f, h, l);
        *(bf16x8*)&sBh[row * PADK + ch * 8] = h;
        *(bf16x8*)&sBl[row * PADK + ch * 8] = l;
      }
    }
    __syncthreads();
    bf16x8 ah[4], al[4], bh[5], bl[5];
#pragma unroll
    for (int mt = 0; mt < 4; ++mt) {
      int o = (wm * 64 + mt * 16 + lr) * PADK + kc;
      ah[mt] = *(const bf16x8*)&sAh[o];
      al[mt] = *(const bf16x8*)&sAl[o];
    }
#pragma unroll
    for (int nt = 0; nt < 5; ++nt) {
      int o = (wn * 80 + nt * 16 + lr) * PADK + kc;
      bh[nt] = *(const bf16x8*)&sBh[o];
      bl[nt] = *(const bf16x8*)&sBl[o];
    }
#pragma unroll
    for (int mt = 0; mt < 4; ++mt)
#pragma unroll
      for (int nt = 0; nt < 5; ++nt) {
        acc[mt][nt] = __builtin_amdgcn_mfma_f32_16x16x32_bf16(ah[mt], bh[nt], acc[mt][nt], 0, 0, 0);
        acc[mt][nt] = __builtin_amdgcn_mfma_f32_16x16x32_bf16(ah[mt], bl[nt], acc[mt][nt], 0, 0, 0);
        acc[mt][nt] = __builtin_amdgcn_mfma_f32_16x16x32_bf16(al[mt], bh[nt], acc[mt][nt], 0, 0, 0);
      }
  }

  // ---- fused LayerNorm epilogue ----
  const int g4 = lane >> 4;
#pragma unroll
  for (int nt = 0; nt < 5; ++nt) {               // + projection bias
    float bv = b_out[wn * 80 + nt * 16 + lr];
#pragma unroll
    for (int mt = 0; mt < 4; ++mt)
#pragma unroll
      for (int r = 0; r < 4; ++r) acc[mt][nt][r] += bv;
  }
#pragma unroll
  for (int mt = 0; mt < 4; ++mt)                 // per-row partial sums (this wave's 80 cols)
#pragma unroll
    for (int r = 0; r < 4; ++r) {
      float s = 0.f, qq = 0.f;
#pragma unroll
      for (int nt = 0; nt < 5; ++nt) { float v = acc[mt][nt][r]; s += v; qq += v * v; }
#pragma unroll
      for (int off = 1; off < 16; off <<= 1) {   // reduce across the 16 col-lanes
        s  += __shfl_xor(s, off);
        qq += __shfl_xor(qq, off);
      }
      if (lr == 0) {
        int row = wm * 64 + mt * 16 + g4 * 4 + r;
        sSum[row * 4 + wn] = s;
        sSq[row * 4 + wn]  = qq;
      }
    }
  __syncthreads();
  if (tid < 128) {
    float s  = sSum[tid * 4] + sSum[tid * 4 + 1] + sSum[tid * 4 + 2] + sSum[tid * 4 + 3];
    float qq = sSq[tid * 4]  + sSq[tid * 4 + 1]  + sSq[tid * 4 + 2]  + sSq[tid * 4 + 3];
    float mean = s * (1.f / 320.f);
    float var  = qq * (1.f / 320.f) - mean * mean;
    sMean[tid] = mean;
    sRstd[tid] = rsqrtf(var + 1e-5f);
  }
  __syncthreads();
#pragma unroll
  for (int nt = 0; nt < 5; ++nt) {
    int col = wn * 80 + nt * 16 + lr;
    float gv = ln_g[col], bv = ln_b[col];
#pragma unroll
    for (int mt = 0; mt < 4; ++mt)
#pragma unroll
      for (int r = 0; r < 4; ++r) {
        int row = wm * 64 + mt * 16 + g4 * 4 + r;
        out[(size_t)(bm * 128 + row) * DIM + col] =
            (acc[mt][nt][r] - sMean[row]) * sRstd[row] * gv + bv;
      }
  }
}

// ---------------------------------------------------------------------------
// Launcher. Workspace: [0,256) flag; [256, 256+80M) oh; then ol.  ~160 MB.
// ---------------------------------------------------------------------------
extern "C" void kernel_launch(void* const* d_in, const int* in_sizes, int n_in,
                              void* d_out, int out_size, void* d_ws, size_t ws_size,
                              hipStream_t stream) {
  (void)n_in; (void)out_size; (void)ws_size;
  const float* x     = (const float*)d_in[0];
  const void*  pmask = d_in[1];                  // bool or int32 — detected at runtime
  const float* w_in  = (const float*)d_in[2];
  const float* b_in  = (const float*)d_in[3];
  const float* w_out = (const float*)d_in[4];
  const float* b_out = (const float*)d_in[5];
  const float* ln_g  = (const float*)d_in[6];
  const float* ln_b  = (const float*)d_in[7];
  float* out = (float*)d_out;

  char* ws = (char*)d_ws;
  int*    flag = (int*)ws;
  __bf16* oh = (__bf16*)(ws + 256);
  __bf16* ol = oh + (size_t)MROWS * DIM;

  detect_mask_kernel<<<1, 1024, 0, stream>>>(
      (const unsigned char*)pmask, in_sizes[1], flag);
  qkv_attn_kernel<<<NSEQ, 512, 0, stream>>>(
      x, w_in, b_in, pmask, flag, oh, ol);
  proj_ln_kernel<<<MROWS / 128, 512, 0, stream>>>(
      oh, ol, w_out, b_out, ln_g, ln_b, out);
}